// Round 1
// baseline (381.895 us; speedup 1.0000x reference)
//
#include <hip/hip_runtime.h>
#include <hip/hip_bf16.h>

// GPT attention block on MI355X: qkv GEMM -> causal flash attn -> proj GEMM.
// All matmuls in bf16 MFMA (16x16x32), fp32 accumulate.
// B=2, T=2048, D=1024, H=16, dh=64.

typedef unsigned short u16;
typedef __attribute__((ext_vector_type(4))) float f32x4;
typedef __attribute__((ext_vector_type(8))) short bf16x8;

__device__ __forceinline__ u16 f2bf(float f) {
  unsigned u = __builtin_bit_cast(unsigned, f);
  u += 0x7FFFu + ((u >> 16) & 1u);
  return (u16)(u >> 16);
}

__device__ __forceinline__ void gl_lds16(const u16* g, u16* l) {
  __builtin_amdgcn_global_load_lds(
      (const __attribute__((address_space(1))) void*)g,
      (__attribute__((address_space(3))) void*)l, 16, 0, 0);
}

// ---------------- cast fp32 -> bf16 (vectorized) ----------------
__global__ __launch_bounds__(256) void cast_bf16_kernel(const float* __restrict__ in,
                                                        u16* __restrict__ out, int n4) {
  int i = blockIdx.x * 256 + threadIdx.x;
  if (i < n4) {
    float4 f = reinterpret_cast<const float4*>(in)[i];
    ushort4 o;
    o.x = f2bf(f.x); o.y = f2bf(f.y); o.z = f2bf(f.z); o.w = f2bf(f.w);
    reinterpret_cast<ushort4*>(out)[i] = o;
  }
}

// ---------------- transpose + cast: in[R][C] f32 -> out[C][R] bf16 ----------------
__global__ __launch_bounds__(256) void transpose_cast(const float* __restrict__ in,
                                                      u16* __restrict__ out, int R, int C) {
  __shared__ float tile[32][33];
  const int c0 = blockIdx.x * 32, r0 = blockIdx.y * 32;
  const int tx = threadIdx.x, ty = threadIdx.y;  // block (32,8)
#pragma unroll
  for (int i = 0; i < 4; ++i)
    tile[ty + 8 * i][tx] = in[(size_t)(r0 + ty + 8 * i) * C + c0 + tx];
  __syncthreads();
#pragma unroll
  for (int i = 0; i < 4; ++i)
    out[(size_t)(c0 + ty + 8 * i) * R + r0 + tx] = f2bf(tile[tx][ty + 8 * i]);
}

// ---------------- bf16 GEMM: C[M][N] = A[M][K] * Bt[N][K]^T + bias ----------------
// MODE 0: scatter epilogue to Qh[B,H,T,dh], Kh[B,H,T,dh], VhT[B,H,dh,T] (bf16)
// MODE 1: plain fp32 out
template <int MODE>
__global__ __launch_bounds__(256) void gemm_bf16(
    const u16* __restrict__ A, const u16* __restrict__ Bt, const float* __restrict__ bias,
    float* __restrict__ outF, u16* __restrict__ Qh, u16* __restrict__ Kh, u16* __restrict__ VhT,
    int M, int N, int K) {
  __shared__ u16 As[128 * 32];
  __shared__ u16 Bs[128 * 32];
  const int tid = threadIdx.x;
  const int wave = tid >> 6, lane = tid & 63;
  const int kg = lane >> 4, rr = lane & 15;
  const int wm = wave >> 1, wn = wave & 1;
  const int rowA0 = blockIdx.y * 128, colB0 = blockIdx.x * 128;

  const f32x4 z4 = {0.f, 0.f, 0.f, 0.f};
  f32x4 acc[4][4];
#pragma unroll
  for (int i = 0; i < 4; ++i)
#pragma unroll
    for (int j = 0; j < 4; ++j) acc[i][j] = z4;

  const int r_st = tid >> 2;          // staging row (i*64 + r_st)
  const int c_st = (tid & 3) * 8;     // staging k offset

  for (int k0 = 0; k0 < K; k0 += 32) {
#pragma unroll
    for (int i = 0; i < 2; ++i) {
      gl_lds16(A + (size_t)(rowA0 + i * 64 + r_st) * K + k0 + c_st,
               As + (i * 256 + (wave << 6)) * 8);
      gl_lds16(Bt + (size_t)(colB0 + i * 64 + r_st) * K + k0 + c_st,
               Bs + (i * 256 + (wave << 6)) * 8);
    }
    __syncthreads();

    bf16x8 af[4], bf[4];
#pragma unroll
    for (int mi = 0; mi < 4; ++mi)
      af[mi] = *reinterpret_cast<const bf16x8*>(&As[(wm * 64 + mi * 16 + rr) * 32 + kg * 8]);
#pragma unroll
    for (int ni = 0; ni < 4; ++ni)
      bf[ni] = *reinterpret_cast<const bf16x8*>(&Bs[(wn * 64 + ni * 16 + rr) * 32 + kg * 8]);
#pragma unroll
    for (int mi = 0; mi < 4; ++mi)
#pragma unroll
      for (int ni = 0; ni < 4; ++ni)
        acc[mi][ni] = __builtin_amdgcn_mfma_f32_16x16x32_bf16(af[mi], bf[ni], acc[mi][ni], 0, 0, 0);
    __syncthreads();
  }

#pragma unroll
  for (int mi = 0; mi < 4; ++mi) {
#pragma unroll
    for (int ni = 0; ni < 4; ++ni) {
      const int col = colB0 + wn * 64 + ni * 16 + rr;
      const float bcol = bias[col];
      f32x4 a = acc[mi][ni];
#pragma unroll
      for (int v = 0; v < 4; ++v) {
        const int row = rowA0 + wm * 64 + mi * 16 + kg * 4 + v;
        const float val = a[v] + bcol;
        if (MODE == 1) {
          outF[(size_t)row * N + col] = val;
        } else {
          const int b = row >> 11, t = row & 2047;
          const int which = col >> 10, d = col & 1023;
          const int h = d >> 6, dd = d & 63;
          const size_t bh = (size_t)(b * 16 + h);
          if (which == 0)
            Qh[(bh * 2048 + t) * 64 + dd] = f2bf(val);
          else if (which == 1)
            Kh[(bh * 2048 + t) * 64 + dd] = f2bf(val);
          else
            VhT[(bh * 64 + dd) * 2048 + t] = f2bf(val);
        }
      }
    }
  }
}

// ---------------- causal flash attention ----------------
// grid (qtile=T/64, bh=B*H), 256 threads (4 waves). Wave w owns 16 q-rows.
__global__ __launch_bounds__(256) void attn_fwd(const u16* __restrict__ Qh,
                                                const u16* __restrict__ Kh,
                                                const u16* __restrict__ VhT,
                                                u16* __restrict__ Ab) {
  __shared__ u16 Pl[4][16 * 64];
  const int tid = threadIdx.x;
  const int wave = tid >> 6, lane = tid & 63;
  const int kg = lane >> 4, rr = lane & 15;
  const int qtile = blockIdx.x, bh = blockIdx.y;
  const int q0 = qtile * 64 + wave * 16;
  const size_t kvbase = (size_t)bh * 2048;

  // Q fragments in registers (A-operand: row = lane&15, k = (lane>>4)*8+j)
  bf16x8 aq[2];
#pragma unroll
  for (int kc = 0; kc < 2; ++kc)
    aq[kc] = *reinterpret_cast<const bf16x8*>(&Qh[(kvbase + q0 + rr) * 64 + kc * 32 + kg * 8]);

  const f32x4 z4 = {0.f, 0.f, 0.f, 0.f};
  f32x4 o[4];
  float m_run[4], l_run[4];
#pragma unroll
  for (int i = 0; i < 4; ++i) { o[i] = z4; m_run[i] = -1e30f; l_run[i] = 0.f; }

  const int nkv = qtile + 1;
  for (int kvb = 0; kvb < nkv; ++kvb) {
    const int kv0 = kvb * 64;
    // S = Q K^T / 8  (16 q-rows x 64 kv-cols per wave)
    f32x4 s[4];
#pragma unroll
    for (int ci = 0; ci < 4; ++ci) {
      s[ci] = z4;
#pragma unroll
      for (int kc = 0; kc < 2; ++kc) {
        bf16x8 bk = *reinterpret_cast<const bf16x8*>(
            &Kh[(kvbase + kv0 + ci * 16 + rr) * 64 + kc * 32 + kg * 8]);
        s[ci] = __builtin_amdgcn_mfma_f32_16x16x32_bf16(aq[kc], bk, s[ci], 0, 0, 0);
      }
      s[ci] *= 0.125f;
    }
    // causal mask (only diagonal block)
    if (kvb == qtile) {
#pragma unroll
      for (int ci = 0; ci < 4; ++ci)
#pragma unroll
        for (int v = 0; v < 4; ++v) {
          const int qrow = q0 + kg * 4 + v;
          const int kcol = kv0 + ci * 16 + rr;
          if (kcol > qrow) s[ci][v] = -1e30f;
        }
    }
    // online softmax (row r lives in the 16 lanes sharing lane>>4; 4 rows/lane)
    float mn[4], sc[4], rsum[4];
#pragma unroll
    for (int v = 0; v < 4; ++v) {
      float r = fmaxf(fmaxf(s[0][v], s[1][v]), fmaxf(s[2][v], s[3][v]));
      r = fmaxf(r, __shfl_xor(r, 1));
      r = fmaxf(r, __shfl_xor(r, 2));
      r = fmaxf(r, __shfl_xor(r, 4));
      r = fmaxf(r, __shfl_xor(r, 8));
      mn[v] = fmaxf(m_run[v], r);
      sc[v] = __expf(m_run[v] - mn[v]);
      rsum[v] = 0.f;
    }
#pragma unroll
    for (int ci = 0; ci < 4; ++ci)
#pragma unroll
      for (int v = 0; v < 4; ++v) {
        const float p = __expf(s[ci][v] - mn[v]);
        s[ci][v] = p;
        rsum[v] += p;
      }
#pragma unroll
    for (int v = 0; v < 4; ++v) {
      float r = rsum[v];
      r += __shfl_xor(r, 1);
      r += __shfl_xor(r, 2);
      r += __shfl_xor(r, 4);
      r += __shfl_xor(r, 8);
      l_run[v] = l_run[v] * sc[v] + r;
      m_run[v] = mn[v];
    }
#pragma unroll
    for (int ci = 0; ci < 4; ++ci)
#pragma unroll
      for (int v = 0; v < 4; ++v) o[ci][v] *= sc[v];

    // P (D-layout) -> LDS bf16 -> reload as A-operand fragments
#pragma unroll
    for (int ci = 0; ci < 4; ++ci)
#pragma unroll
      for (int v = 0; v < 4; ++v)
        Pl[wave][(kg * 4 + v) * 64 + ci * 16 + rr] = f2bf(s[ci][v]);
    asm volatile("s_waitcnt lgkmcnt(0)" ::: "memory");

    bf16x8 pa[2];
#pragma unroll
    for (int kc = 0; kc < 2; ++kc)
      pa[kc] = *reinterpret_cast<const bf16x8*>(&Pl[wave][rr * 64 + kc * 32 + kg * 8]);
#pragma unroll
    for (int ci = 0; ci < 4; ++ci)
#pragma unroll
      for (int kc = 0; kc < 2; ++kc) {
        bf16x8 bv = *reinterpret_cast<const bf16x8*>(
            &VhT[((size_t)bh * 64 + ci * 16 + rr) * 2048 + kv0 + kc * 32 + kg * 8]);
        o[ci] = __builtin_amdgcn_mfma_f32_16x16x32_bf16(pa[kc], bv, o[ci], 0, 0, 0);
      }
  }

  // epilogue: O/l, merge heads -> Ab[B,T,D] bf16
  const int b = bh >> 4, h = bh & 15;
#pragma unroll
  for (int ci = 0; ci < 4; ++ci)
#pragma unroll
    for (int v = 0; v < 4; ++v) {
      const float val = o[ci][v] / l_run[v];
      Ab[((size_t)b * 2048 + q0 + kg * 4 + v) * 1024 + h * 64 + ci * 16 + rr] = f2bf(val);
    }
}

extern "C" void kernel_launch(void* const* d_in, const int* in_sizes, int n_in,
                              void* d_out, int out_size, void* d_ws, size_t ws_size,
                              hipStream_t stream) {
  const float* x      = (const float*)d_in[0];
  const float* W_attn = (const float*)d_in[1];
  const float* b_attn = (const float*)d_in[2];
  const float* W_proj = (const float*)d_in[3];
  const float* b_proj = (const float*)d_in[4];
  float* out = (float*)d_out;

  u16* xb  = (u16*)d_ws;                      // [4096][1024] bf16
  u16* Wat = xb + (size_t)4096 * 1024;        // [3072][1024] bf16 (W_attn^T)
  u16* Wpt = Wat + (size_t)3072 * 1024;       // [1024][1024] bf16 (W_proj^T)
  u16* Qh  = Wpt + (size_t)1024 * 1024;       // [2,16,2048,64] bf16
  u16* Kh  = Qh + (size_t)4194304;            // [2,16,2048,64] bf16
  u16* VhT = Kh + (size_t)4194304;            // [2,16,64,2048] bf16
  u16* Ab  = VhT + (size_t)4194304;           // [4096][1024] bf16

  cast_bf16_kernel<<<4096, 256, 0, stream>>>(x, xb, 4096 * 1024 / 4);
  transpose_cast<<<dim3(96, 32), dim3(32, 8), 0, stream>>>(W_attn, Wat, 1024, 3072);
  transpose_cast<<<dim3(32, 32), dim3(32, 8), 0, stream>>>(W_proj, Wpt, 1024, 1024);
  gemm_bf16<0><<<dim3(24, 32), 256, 0, stream>>>(xb, Wat, b_attn, nullptr, Qh, Kh, VhT,
                                                 4096, 3072, 1024);
  attn_fwd<<<dim3(32, 32), 256, 0, stream>>>(Qh, Kh, VhT, Ab);
  gemm_bf16<1><<<dim3(8, 32), 256, 0, stream>>>(Ab, Wpt, b_proj, out, nullptr, nullptr, nullptr,
                                                4096, 1024, 1024);
}

// Round 2
// 247.051 us; speedup vs baseline: 1.5458x; 1.5458x over previous
//
#include <hip/hip_runtime.h>
#include <hip/hip_bf16.h>

// GPT attention block on MI355X: qkv GEMM -> causal flash attn -> proj GEMM.
// B=2, T=2048, D=1024, H=16, dh=64.
// Attn: swapped-QK 32x32x16 MFMA, in-register online softmax (T12), no LDS.

typedef unsigned short u16;
typedef unsigned int u32;
typedef __attribute__((ext_vector_type(4))) float f32x4;
typedef __attribute__((ext_vector_type(16))) float f32x16;
typedef __attribute__((ext_vector_type(8))) short bf16x8;
typedef __attribute__((ext_vector_type(4))) int i32x4;

__device__ __forceinline__ u16 f2bf(float f) {
  unsigned u = __builtin_bit_cast(unsigned, f);
  u += 0x7FFFu + ((u >> 16) & 1u);
  return (u16)(u >> 16);
}

__device__ __forceinline__ u32 pack_bf2(float lo, float hi) {
  return (u32)f2bf(lo) | ((u32)f2bf(hi) << 16);
}

__device__ __forceinline__ void gl_lds16(const u16* g, u16* l) {
  __builtin_amdgcn_global_load_lds(
      (const __attribute__((address_space(1))) void*)g,
      (__attribute__((address_space(3))) void*)l, 16, 0, 0);
}

// ---------------- cast fp32 -> bf16 (vectorized) ----------------
__global__ __launch_bounds__(256) void cast_bf16_kernel(const float* __restrict__ in,
                                                        u16* __restrict__ out, int n4) {
  int i = blockIdx.x * 256 + threadIdx.x;
  if (i < n4) {
    float4 f = reinterpret_cast<const float4*>(in)[i];
    ushort4 o;
    o.x = f2bf(f.x); o.y = f2bf(f.y); o.z = f2bf(f.z); o.w = f2bf(f.w);
    reinterpret_cast<ushort4*>(out)[i] = o;
  }
}

// ---------------- transpose + cast: in[R][C] f32 -> out[C][R] bf16 ----------------
__global__ __launch_bounds__(256) void transpose_cast(const float* __restrict__ in,
                                                      u16* __restrict__ out, int R, int C) {
  __shared__ float tile[32][33];
  const int c0 = blockIdx.x * 32, r0 = blockIdx.y * 32;
  const int tx = threadIdx.x, ty = threadIdx.y;  // block (32,8)
#pragma unroll
  for (int i = 0; i < 4; ++i)
    tile[ty + 8 * i][tx] = in[(size_t)(r0 + ty + 8 * i) * C + c0 + tx];
  __syncthreads();
#pragma unroll
  for (int i = 0; i < 4; ++i)
    out[(size_t)(c0 + ty + 8 * i) * R + r0 + tx] = f2bf(tile[tx][ty + 8 * i]);
}

// ---------------- bf16 GEMM: C[M][N] = A[M][K] * Bt[N][K]^T + bias ----------------
template <int MODE>
__global__ __launch_bounds__(256) void gemm_bf16(
    const u16* __restrict__ A, const u16* __restrict__ Bt, const float* __restrict__ bias,
    float* __restrict__ outF, u16* __restrict__ Qh, u16* __restrict__ Kh, u16* __restrict__ VhT,
    int M, int N, int K) {
  __shared__ u16 As[128 * 32];
  __shared__ u16 Bs[128 * 32];
  const int tid = threadIdx.x;
  const int wave = tid >> 6, lane = tid & 63;
  const int kg = lane >> 4, rr = lane & 15;
  const int wm = wave >> 1, wn = wave & 1;
  const int rowA0 = blockIdx.y * 128, colB0 = blockIdx.x * 128;

  const f32x4 z4 = {0.f, 0.f, 0.f, 0.f};
  f32x4 acc[4][4];
#pragma unroll
  for (int i = 0; i < 4; ++i)
#pragma unroll
    for (int j = 0; j < 4; ++j) acc[i][j] = z4;

  const int r_st = tid >> 2;
  const int c_st = (tid & 3) * 8;

  for (int k0 = 0; k0 < K; k0 += 32) {
#pragma unroll
    for (int i = 0; i < 2; ++i) {
      gl_lds16(A + (size_t)(rowA0 + i * 64 + r_st) * K + k0 + c_st,
               As + (i * 256 + (wave << 6)) * 8);
      gl_lds16(Bt + (size_t)(colB0 + i * 64 + r_st) * K + k0 + c_st,
               Bs + (i * 256 + (wave << 6)) * 8);
    }
    __syncthreads();

    bf16x8 af[4], bfr[4];
#pragma unroll
    for (int mi = 0; mi < 4; ++mi)
      af[mi] = *reinterpret_cast<const bf16x8*>(&As[(wm * 64 + mi * 16 + rr) * 32 + kg * 8]);
#pragma unroll
    for (int ni = 0; ni < 4; ++ni)
      bfr[ni] = *reinterpret_cast<const bf16x8*>(&Bs[(wn * 64 + ni * 16 + rr) * 32 + kg * 8]);
#pragma unroll
    for (int mi = 0; mi < 4; ++mi)
#pragma unroll
      for (int ni = 0; ni < 4; ++ni)
        acc[mi][ni] = __builtin_amdgcn_mfma_f32_16x16x32_bf16(af[mi], bfr[ni], acc[mi][ni], 0, 0, 0);
    __syncthreads();
  }

#pragma unroll
  for (int mi = 0; mi < 4; ++mi) {
#pragma unroll
    for (int ni = 0; ni < 4; ++ni) {
      const int col = colB0 + wn * 64 + ni * 16 + rr;
      const float bcol = bias[col];
      f32x4 a = acc[mi][ni];
#pragma unroll
      for (int v = 0; v < 4; ++v) {
        const int row = rowA0 + wm * 64 + mi * 16 + kg * 4 + v;
        const float val = a[v] + bcol;
        if (MODE == 1) {
          outF[(size_t)row * N + col] = val;
        } else {
          const int b = row >> 11, t = row & 2047;
          const int which = col >> 10, d = col & 1023;
          const int h = d >> 6, dd = d & 63;
          const size_t bh = (size_t)(b * 16 + h);
          if (which == 0)
            Qh[(bh * 2048 + t) * 64 + dd] = f2bf(val);
          else if (which == 1)
            Kh[(bh * 2048 + t) * 64 + dd] = f2bf(val);
          else
            VhT[(bh * 64 + dd) * 2048 + t] = f2bf(val);
        }
      }
    }
  }
}

// ---------------- causal flash attention, swapped-QK, no LDS ----------------
// One wave = 32 q-rows of one (bh). Grid: 512 blocks x 4 waves = 2048 wave-tasks.
// task -> qi = task>>5 (qtile = 63-qi, longest first), bh = task&31.
__global__ __launch_bounds__(256) void attn_fwd(const u16* __restrict__ Qh,
                                                const u16* __restrict__ Kh,
                                                const u16* __restrict__ VhT,
                                                u16* __restrict__ Ab) {
  const int tid = threadIdx.x;
  const int wave = tid >> 6, lane = tid & 63;
  const int lq = lane & 31, hi = lane >> 5;
  const int task = blockIdx.x * 4 + wave;
  const int qi = task >> 5;
  const int bh = task & 31;
  const int qtile = 63 - qi;
  const int q0 = qtile * 32;
  const int myq = q0 + lq;
  const size_t kvbase = (size_t)bh * 2048;

  // Q as MFMA B-operand: col=q(lane&31), k = hi*8 + j (+16*ks over dh=64)
  bf16x8 qf[4];
  {
    const u16* qptr = Qh + (kvbase + q0 + lq) * 64 + hi * 8;
#pragma unroll
    for (int ks = 0; ks < 4; ++ks)
      qf[ks] = *reinterpret_cast<const bf16x8*>(qptr + ks * 16);
  }

  f32x16 oA, oB;  // O^T accumulators: dh tiles [0,32) and [32,64); col=q, row=dh'
#pragma unroll
  for (int i = 0; i < 16; ++i) { oA[i] = 0.f; oB[i] = 0.f; }
  float m = -1e30f, l = 0.f;

  const int n64 = (q0 + 32 + 63) >> 6;
  for (int kvb = 0; kvb < n64; ++kvb) {
    const int kv0 = kvb * 64;

    // --- load K (A-operand: row=kv, k=hi*8+j) and V (A-operand: row=dh, k=kv) ---
    const u16* kptr = Kh + (kvbase + kv0 + lq) * 64 + hi * 8;
    bf16x8 kfA[4], kfB[4];
#pragma unroll
    for (int ks = 0; ks < 4; ++ks) {
      kfA[ks] = *reinterpret_cast<const bf16x8*>(kptr + ks * 16);
      kfB[ks] = *reinterpret_cast<const bf16x8*>(kptr + 2048 + ks * 16);  // +32 rows
    }
    const u16* vptr = VhT + ((size_t)bh * 64 + lq) * 2048 + kv0 + hi * 8;
    bf16x8 vfA[4], vfB[4];
#pragma unroll
    for (int ks = 0; ks < 4; ++ks) {
      vfA[ks] = *reinterpret_cast<const bf16x8*>(vptr + ks * 16);
      vfB[ks] = *reinterpret_cast<const bf16x8*>(vptr + 32 * 2048 + ks * 16);
    }

    // --- S^T = K Q^T : col=q, row kv = (r&3)+8*(r>>2)+4*hi ---
    f32x16 sA, sB;
#pragma unroll
    for (int i = 0; i < 16; ++i) { sA[i] = 0.f; sB[i] = 0.f; }
#pragma unroll
    for (int ks = 0; ks < 4; ++ks)
      sA = __builtin_amdgcn_mfma_f32_32x32x16_bf16(kfA[ks], qf[ks], sA, 0, 0, 0);
#pragma unroll
    for (int ks = 0; ks < 4; ++ks)
      sB = __builtin_amdgcn_mfma_f32_32x32x16_bf16(kfB[ks], qf[ks], sB, 0, 0, 0);

    // --- causal mask (last block only) ---
    if (kvb == n64 - 1) {
#pragma unroll
      for (int r = 0; r < 16; ++r) {
        const int kvA = kv0 + (r & 3) + 8 * (r >> 2) + 4 * hi;
        if (kvA > myq) sA[r] = -1e30f;
        if (kvA + 32 > myq) sB[r] = -1e30f;
      }
    }

    // --- online softmax: each lane owns one q-column; partner is lane^32 ---
    float pmax = -1e30f;
#pragma unroll
    for (int r = 0; r < 16; ++r) pmax = fmaxf(pmax, fmaxf(sA[r], sB[r]));
    pmax = fmaxf(pmax, __shfl_xor(pmax, 32));
    const float mn = fmaxf(m, pmax);
    const float sc = __expf((m - mn) * 0.125f);
    const float mn8 = mn * 0.125f;
    float rsum = 0.f;
#pragma unroll
    for (int r = 0; r < 16; ++r) {
      const float pa = __expf(__builtin_fmaf(sA[r], 0.125f, -mn8));
      const float pb = __expf(__builtin_fmaf(sB[r], 0.125f, -mn8));
      sA[r] = pa; sB[r] = pb;
      rsum += pa + pb;
    }
    rsum += __shfl_xor(rsum, 32);
    l = l * sc + rsum;
    m = mn;
    oA *= sc;
    oB *= sc;

    // --- P^T -> bf16 B-operand frags via pack + permlane32_swap (T12) ---
    u32 pkA[8], pkB[8];
#pragma unroll
    for (int i = 0; i < 8; ++i) {
      pkA[i] = pack_bf2(sA[2 * i], sA[2 * i + 1]);
      pkB[i] = pack_bf2(sB[2 * i], sB[2 * i + 1]);
    }
    bf16x8 pf[4];
    {
      auto w0 = __builtin_amdgcn_permlane32_swap(pkA[0], pkA[2], false, false);
      auto w1 = __builtin_amdgcn_permlane32_swap(pkA[1], pkA[3], false, false);
      i32x4 t0 = {(int)w0[0], (int)w1[0], (int)w0[1], (int)w1[1]};
      pf[0] = __builtin_bit_cast(bf16x8, t0);
      auto w2 = __builtin_amdgcn_permlane32_swap(pkA[4], pkA[6], false, false);
      auto w3 = __builtin_amdgcn_permlane32_swap(pkA[5], pkA[7], false, false);
      i32x4 t1 = {(int)w2[0], (int)w3[0], (int)w2[1], (int)w3[1]};
      pf[1] = __builtin_bit_cast(bf16x8, t1);
      auto w4 = __builtin_amdgcn_permlane32_swap(pkB[0], pkB[2], false, false);
      auto w5 = __builtin_amdgcn_permlane32_swap(pkB[1], pkB[3], false, false);
      i32x4 t2 = {(int)w4[0], (int)w5[0], (int)w4[1], (int)w5[1]};
      pf[2] = __builtin_bit_cast(bf16x8, t2);
      auto w6 = __builtin_amdgcn_permlane32_swap(pkB[4], pkB[6], false, false);
      auto w7 = __builtin_amdgcn_permlane32_swap(pkB[5], pkB[7], false, false);
      i32x4 t3 = {(int)w6[0], (int)w7[0], (int)w6[1], (int)w7[1]};
      pf[3] = __builtin_bit_cast(bf16x8, t3);
    }

    // --- O^T += V^T P^T ---
#pragma unroll
    for (int ks = 0; ks < 4; ++ks)
      oA = __builtin_amdgcn_mfma_f32_32x32x16_bf16(vfA[ks], pf[ks], oA, 0, 0, 0);
#pragma unroll
    for (int ks = 0; ks < 4; ++ks)
      oB = __builtin_amdgcn_mfma_f32_32x32x16_bf16(vfB[ks], pf[ks], oB, 0, 0, 0);
  }

  // --- epilogue: O^T/l -> Ab[B,T,D] bf16 (merge heads) ---
  const float inv = 1.0f / l;
  const int b = bh >> 4, h = bh & 15;
  u16* base = Ab + ((size_t)b * 2048 + myq) * 1024 + h * 64;
#pragma unroll
  for (int g = 0; g < 4; ++g) {
    const int dh0 = 8 * g + 4 * hi;
    ushort4 wa, wb;
    wa.x = f2bf(oA[4 * g + 0] * inv); wa.y = f2bf(oA[4 * g + 1] * inv);
    wa.z = f2bf(oA[4 * g + 2] * inv); wa.w = f2bf(oA[4 * g + 3] * inv);
    wb.x = f2bf(oB[4 * g + 0] * inv); wb.y = f2bf(oB[4 * g + 1] * inv);
    wb.z = f2bf(oB[4 * g + 2] * inv); wb.w = f2bf(oB[4 * g + 3] * inv);
    *reinterpret_cast<ushort4*>(base + dh0) = wa;
    *reinterpret_cast<ushort4*>(base + 32 + dh0) = wb;
  }
}

extern "C" void kernel_launch(void* const* d_in, const int* in_sizes, int n_in,
                              void* d_out, int out_size, void* d_ws, size_t ws_size,
                              hipStream_t stream) {
  const float* x      = (const float*)d_in[0];
  const float* W_attn = (const float*)d_in[1];
  const float* b_attn = (const float*)d_in[2];
  const float* W_proj = (const float*)d_in[3];
  const float* b_proj = (const float*)d_in[4];
  float* out = (float*)d_out;

  u16* xb  = (u16*)d_ws;                      // [4096][1024] bf16
  u16* Wat = xb + (size_t)4096 * 1024;        // [3072][1024] bf16 (W_attn^T)
  u16* Wpt = Wat + (size_t)3072 * 1024;       // [1024][1024] bf16 (W_proj^T)
  u16* Qh  = Wpt + (size_t)1024 * 1024;       // [2,16,2048,64] bf16
  u16* Kh  = Qh + (size_t)4194304;            // [2,16,2048,64] bf16
  u16* VhT = Kh + (size_t)4194304;            // [2,16,64,2048] bf16
  u16* Ab  = VhT + (size_t)4194304;           // [4096][1024] bf16

  cast_bf16_kernel<<<4096, 256, 0, stream>>>(x, xb, 4096 * 1024 / 4);
  transpose_cast<<<dim3(96, 32), dim3(32, 8), 0, stream>>>(W_attn, Wat, 1024, 3072);
  transpose_cast<<<dim3(32, 32), dim3(32, 8), 0, stream>>>(W_proj, Wpt, 1024, 1024);
  gemm_bf16<0><<<dim3(24, 32), 256, 0, stream>>>(xb, Wat, b_attn, nullptr, Qh, Kh, VhT,
                                                 4096, 3072, 1024);
  attn_fwd<<<dim3(512), 256, 0, stream>>>(Qh, Kh, VhT, Ab);
  gemm_bf16<1><<<dim3(8, 32), 256, 0, stream>>>(Ab, Wpt, b_proj, out, nullptr, nullptr, nullptr,
                                                4096, 1024, 1024);
}

// Round 3
// 225.458 us; speedup vs baseline: 1.6939x; 1.0958x over previous
//
#include <hip/hip_runtime.h>
#include <hip/hip_bf16.h>

// GPT attention block on MI355X: qkv GEMM -> causal flash attn -> proj GEMM.
// B=2, T=2048, D=1024, H=16, dh=64.
// Attn: swapped-QK 32x32x16 MFMA, in-register softmax (T12), defer-rescale (T13),
//       intra-block split-KV (4 waves share one qtile's KV range, LDS combine).

typedef unsigned short u16;
typedef unsigned int u32;
typedef __attribute__((ext_vector_type(4))) float f32x4;
typedef __attribute__((ext_vector_type(16))) float f32x16;
typedef __attribute__((ext_vector_type(8))) short bf16x8;
typedef __attribute__((ext_vector_type(4))) int i32x4;

__device__ __forceinline__ u16 f2bf(float f) {
  unsigned u = __builtin_bit_cast(unsigned, f);
  u += 0x7FFFu + ((u >> 16) & 1u);
  return (u16)(u >> 16);
}

__device__ __forceinline__ u32 pack_bf2(float lo, float hi) {
  return (u32)f2bf(lo) | ((u32)f2bf(hi) << 16);
}

__device__ __forceinline__ void gl_lds16(const u16* g, u16* l) {
  __builtin_amdgcn_global_load_lds(
      (const __attribute__((address_space(1))) void*)g,
      (__attribute__((address_space(3))) void*)l, 16, 0, 0);
}

// ---------------- cast fp32 -> bf16 (vectorized) ----------------
__global__ __launch_bounds__(256) void cast_bf16_kernel(const float* __restrict__ in,
                                                        u16* __restrict__ out, int n4) {
  int i = blockIdx.x * 256 + threadIdx.x;
  if (i < n4) {
    float4 f = reinterpret_cast<const float4*>(in)[i];
    ushort4 o;
    o.x = f2bf(f.x); o.y = f2bf(f.y); o.z = f2bf(f.z); o.w = f2bf(f.w);
    reinterpret_cast<ushort4*>(out)[i] = o;
  }
}

// ---------------- transpose + cast: in[R][C] f32 -> out[C][R] bf16 ----------------
__global__ __launch_bounds__(256) void transpose_cast(const float* __restrict__ in,
                                                      u16* __restrict__ out, int R, int C) {
  __shared__ float tile[32][33];
  const int c0 = blockIdx.x * 32, r0 = blockIdx.y * 32;
  const int tx = threadIdx.x, ty = threadIdx.y;  // block (32,8)
#pragma unroll
  for (int i = 0; i < 4; ++i)
    tile[ty + 8 * i][tx] = in[(size_t)(r0 + ty + 8 * i) * C + c0 + tx];
  __syncthreads();
#pragma unroll
  for (int i = 0; i < 4; ++i)
    out[(size_t)(c0 + ty + 8 * i) * R + r0 + tx] = f2bf(tile[tx][ty + 8 * i]);
}

// ---------------- bf16 GEMM 128x128: qkv projection, scatter epilogue ----------------
// Writes Qh (pre-scaled by 1/8), Kh [B,H,T,dh], VhT [B,H,dh,T].
__global__ __launch_bounds__(256) void gemm_qkv(
    const u16* __restrict__ A, const u16* __restrict__ Bt, const float* __restrict__ bias,
    u16* __restrict__ Qh, u16* __restrict__ Kh, u16* __restrict__ VhT, int K) {
  __shared__ u16 As[128 * 32];
  __shared__ u16 Bs[128 * 32];
  const int tid = threadIdx.x;
  const int wave = tid >> 6, lane = tid & 63;
  const int kg = lane >> 4, rr = lane & 15;
  const int wm = wave >> 1, wn = wave & 1;
  // XCD-aware bijective swizzle (nwg = 24*32 = 768, %8 == 0)
  const int nwg = gridDim.x * gridDim.y;
  const int lin = blockIdx.y * gridDim.x + blockIdx.x;
  const int swz = (lin & 7) * (nwg >> 3) + (lin >> 3);
  const int bx = swz % gridDim.x, by = swz / gridDim.x;
  const int rowA0 = by * 128, colB0 = bx * 128;

  const f32x4 z4 = {0.f, 0.f, 0.f, 0.f};
  f32x4 acc[4][4];
#pragma unroll
  for (int i = 0; i < 4; ++i)
#pragma unroll
    for (int j = 0; j < 4; ++j) acc[i][j] = z4;

  const int r_st = tid >> 2;
  const int c_st = (tid & 3) * 8;

  for (int k0 = 0; k0 < K; k0 += 32) {
#pragma unroll
    for (int i = 0; i < 2; ++i) {
      gl_lds16(A + (size_t)(rowA0 + i * 64 + r_st) * K + k0 + c_st,
               As + (i * 256 + (wave << 6)) * 8);
      gl_lds16(Bt + (size_t)(colB0 + i * 64 + r_st) * K + k0 + c_st,
               Bs + (i * 256 + (wave << 6)) * 8);
    }
    __syncthreads();

    bf16x8 af[4], bfr[4];
#pragma unroll
    for (int mi = 0; mi < 4; ++mi)
      af[mi] = *reinterpret_cast<const bf16x8*>(&As[(wm * 64 + mi * 16 + rr) * 32 + kg * 8]);
#pragma unroll
    for (int ni = 0; ni < 4; ++ni)
      bfr[ni] = *reinterpret_cast<const bf16x8*>(&Bs[(wn * 64 + ni * 16 + rr) * 32 + kg * 8]);
#pragma unroll
    for (int mi = 0; mi < 4; ++mi)
#pragma unroll
      for (int ni = 0; ni < 4; ++ni)
        acc[mi][ni] = __builtin_amdgcn_mfma_f32_16x16x32_bf16(af[mi], bfr[ni], acc[mi][ni], 0, 0, 0);
    __syncthreads();
  }

#pragma unroll
  for (int mi = 0; mi < 4; ++mi) {
#pragma unroll
    for (int ni = 0; ni < 4; ++ni) {
      const int col = colB0 + wn * 64 + ni * 16 + rr;
      const float bcol = bias[col];
      f32x4 a = acc[mi][ni];
#pragma unroll
      for (int v = 0; v < 4; ++v) {
        const int row = rowA0 + wm * 64 + mi * 16 + kg * 4 + v;
        const float val = a[v] + bcol;
        const int b = row >> 11, t = row & 2047;
        const int which = col >> 10, d = col & 1023;
        const int h = d >> 6, dd = d & 63;
        const size_t bh = (size_t)(b * 16 + h);
        if (which == 0)
          Qh[(bh * 2048 + t) * 64 + dd] = f2bf(val * 0.125f);  // fold 1/sqrt(dh)
        else if (which == 1)
          Kh[(bh * 2048 + t) * 64 + dd] = f2bf(val);
        else
          VhT[(bh * 64 + dd) * 2048 + t] = f2bf(val);
      }
    }
  }
}

// ---------------- bf16 GEMM 128x64: proj, fp32 out + bias ----------------
__global__ __launch_bounds__(256) void gemm_proj(
    const u16* __restrict__ A, const u16* __restrict__ Bt, const float* __restrict__ bias,
    float* __restrict__ outF, int N, int K) {
  __shared__ u16 As[128 * 32];
  __shared__ u16 Bs[64 * 32];
  const int tid = threadIdx.x;
  const int wave = tid >> 6, lane = tid & 63;
  const int kg = lane >> 4, rr = lane & 15;
  // swizzle (nwg = 16*32 = 512, %8 == 0)
  const int nwg = gridDim.x * gridDim.y;
  const int lin = blockIdx.y * gridDim.x + blockIdx.x;
  const int swz = (lin & 7) * (nwg >> 3) + (lin >> 3);
  const int bx = swz % gridDim.x, by = swz / gridDim.x;
  const int rowA0 = by * 128, colB0 = bx * 64;

  const f32x4 z4 = {0.f, 0.f, 0.f, 0.f};
  f32x4 acc[2][4];
#pragma unroll
  for (int i = 0; i < 2; ++i)
#pragma unroll
    for (int j = 0; j < 4; ++j) acc[i][j] = z4;

  const int r_st = tid >> 2;
  const int c_st = (tid & 3) * 8;

  for (int k0 = 0; k0 < K; k0 += 32) {
#pragma unroll
    for (int i = 0; i < 2; ++i)
      gl_lds16(A + (size_t)(rowA0 + i * 64 + r_st) * K + k0 + c_st,
               As + (i * 256 + (wave << 6)) * 8);
    gl_lds16(Bt + (size_t)(colB0 + r_st) * K + k0 + c_st, Bs + (wave << 6) * 8);
    __syncthreads();

    bf16x8 af[2], bfr[4];
#pragma unroll
    for (int mi = 0; mi < 2; ++mi)
      af[mi] = *reinterpret_cast<const bf16x8*>(&As[(wave * 32 + mi * 16 + rr) * 32 + kg * 8]);
#pragma unroll
    for (int ni = 0; ni < 4; ++ni)
      bfr[ni] = *reinterpret_cast<const bf16x8*>(&Bs[(ni * 16 + rr) * 32 + kg * 8]);
#pragma unroll
    for (int mi = 0; mi < 2; ++mi)
#pragma unroll
      for (int ni = 0; ni < 4; ++ni)
        acc[mi][ni] = __builtin_amdgcn_mfma_f32_16x16x32_bf16(af[mi], bfr[ni], acc[mi][ni], 0, 0, 0);
    __syncthreads();
  }

#pragma unroll
  for (int mi = 0; mi < 2; ++mi) {
#pragma unroll
    for (int ni = 0; ni < 4; ++ni) {
      const int col = colB0 + ni * 16 + rr;
      const float bcol = bias[col];
      f32x4 a = acc[mi][ni];
#pragma unroll
      for (int v = 0; v < 4; ++v) {
        const int row = rowA0 + wave * 32 + mi * 16 + kg * 4 + v;
        outF[(size_t)row * N + col] = a[v] + bcol;
      }
    }
  }
}

// ---------------- causal flash attention, split-KV within block ----------------
// Block = (bh, qtile of 32 q-rows). 4 waves split the qtile's KV blocks (64 wide),
// each builds unnormalized partial (o, m, l); LDS combine -> Ab.
__global__ __launch_bounds__(256) void attn_fwd(const u16* __restrict__ Qh,
                                                const u16* __restrict__ Kh,
                                                const u16* __restrict__ VhT,
                                                u16* __restrict__ Ab) {
  __shared__ float Ol[4][64][33];  // [wave][dh][q-col], padded
  __shared__ float Ml[4][2][32];   // [wave][{m,l}][q-col]
  const int tid = threadIdx.x;
  const int wave = tid >> 6, lane = tid & 63;
  const int lq = lane & 31, hi = lane >> 5;
  const int blk = blockIdx.x;
  const int qi = blk >> 5;          // 0..63, longest first
  const int bh = blk & 31;
  const int qtile = 63 - qi;
  const int q0 = qtile * 32;
  const int myq = q0 + lq;
  const size_t kvbase = (size_t)bh * 2048;

  // per-wave KV chunk: n64 blocks total, split across 4 waves
  const int n64 = (q0 + 32 + 63) >> 6;
  const int base = n64 >> 2, rem = n64 & 3;
  const int cnt = base + (wave < rem ? 1 : 0);
  const int start = wave * base + (wave < rem ? wave : rem);

  // Q as MFMA B-operand (pre-scaled by 1/8): col=q, k = hi*8 + j (+16*ks)
  bf16x8 qf[4];
  {
    const u16* qptr = Qh + (kvbase + q0 + lq) * 64 + hi * 8;
#pragma unroll
    for (int ks = 0; ks < 4; ++ks)
      qf[ks] = *reinterpret_cast<const bf16x8*>(qptr + ks * 16);
  }

  f32x16 oA, oB;  // O^T partial: dh [0,32) and [32,64); col=q, row=dh'
#pragma unroll
  for (int i = 0; i < 16; ++i) { oA[i] = 0.f; oB[i] = 0.f; }
  float m = -1e30f, l = 0.f;

  for (int kvb = start; kvb < start + cnt; ++kvb) {
    const int kv0 = kvb * 64;

    const u16* kptr = Kh + (kvbase + kv0 + lq) * 64 + hi * 8;
    bf16x8 kfA[4], kfB[4];
#pragma unroll
    for (int ks = 0; ks < 4; ++ks) {
      kfA[ks] = *reinterpret_cast<const bf16x8*>(kptr + ks * 16);
      kfB[ks] = *reinterpret_cast<const bf16x8*>(kptr + 2048 + ks * 16);  // +32 rows
    }
    const u16* vptr = VhT + ((size_t)bh * 64 + lq) * 2048 + kv0 + hi * 8;
    bf16x8 vfA[4], vfB[4];
#pragma unroll
    for (int ks = 0; ks < 4; ++ks) {
      vfA[ks] = *reinterpret_cast<const bf16x8*>(vptr + ks * 16);
      vfB[ks] = *reinterpret_cast<const bf16x8*>(vptr + 32 * 2048 + ks * 16);
    }

    // S^T = K Q^T (already scaled): col=q, row kv = (r&3)+8*(r>>2)+4*hi
    f32x16 sA, sB;
#pragma unroll
    for (int i = 0; i < 16; ++i) { sA[i] = 0.f; sB[i] = 0.f; }
#pragma unroll
    for (int ks = 0; ks < 4; ++ks)
      sA = __builtin_amdgcn_mfma_f32_32x32x16_bf16(kfA[ks], qf[ks], sA, 0, 0, 0);
#pragma unroll
    for (int ks = 0; ks < 4; ++ks)
      sB = __builtin_amdgcn_mfma_f32_32x32x16_bf16(kfB[ks], qf[ks], sB, 0, 0, 0);

    // causal mask (last global block only)
    if (kvb == n64 - 1) {
#pragma unroll
      for (int r = 0; r < 16; ++r) {
        const int kvA = kv0 + (r & 3) + 8 * (r >> 2) + 4 * hi;
        if (kvA > myq) sA[r] = -1e30f;
        if (kvA + 32 > myq) sB[r] = -1e30f;
      }
    }

    // online softmax; lane owns one q-column, partner lane^32
    float pmax = -1e30f;
#pragma unroll
    for (int r = 0; r < 16; ++r) pmax = fmaxf(pmax, fmaxf(sA[r], sB[r]));
    pmax = fmaxf(pmax, __shfl_xor(pmax, 32));
    // defer-rescale (T13): skip O/l rescale while max growth <= 8
    if (!__all(pmax - m <= 8.0f)) {
      const float mn = fmaxf(m, pmax);
      const float sc = __expf(m - mn);
      l *= sc;
      oA *= sc;
      oB *= sc;
      m = mn;
    }
    float rsum = 0.f;
#pragma unroll
    for (int r = 0; r < 16; ++r) {
      const float pa = __expf(sA[r] - m);
      const float pb = __expf(sB[r] - m);
      sA[r] = pa; sB[r] = pb;
      rsum += pa + pb;
    }
    rsum += __shfl_xor(rsum, 32);
    l += rsum;

    // P^T -> bf16 B-operand frags via pack + permlane32_swap (T12)
    u32 pkA[8], pkB[8];
#pragma unroll
    for (int i = 0; i < 8; ++i) {
      pkA[i] = pack_bf2(sA[2 * i], sA[2 * i + 1]);
      pkB[i] = pack_bf2(sB[2 * i], sB[2 * i + 1]);
    }
    bf16x8 pf[4];
    {
      auto w0 = __builtin_amdgcn_permlane32_swap(pkA[0], pkA[2], false, false);
      auto w1 = __builtin_amdgcn_permlane32_swap(pkA[1], pkA[3], false, false);
      i32x4 t0 = {(int)w0[0], (int)w1[0], (int)w0[1], (int)w1[1]};
      pf[0] = __builtin_bit_cast(bf16x8, t0);
      auto w2 = __builtin_amdgcn_permlane32_swap(pkA[4], pkA[6], false, false);
      auto w3 = __builtin_amdgcn_permlane32_swap(pkA[5], pkA[7], false, false);
      i32x4 t1 = {(int)w2[0], (int)w3[0], (int)w2[1], (int)w3[1]};
      pf[1] = __builtin_bit_cast(bf16x8, t1);
      auto w4 = __builtin_amdgcn_permlane32_swap(pkB[0], pkB[2], false, false);
      auto w5 = __builtin_amdgcn_permlane32_swap(pkB[1], pkB[3], false, false);
      i32x4 t2 = {(int)w4[0], (int)w5[0], (int)w4[1], (int)w5[1]};
      pf[2] = __builtin_bit_cast(bf16x8, t2);
      auto w6 = __builtin_amdgcn_permlane32_swap(pkB[4], pkB[6], false, false);
      auto w7 = __builtin_amdgcn_permlane32_swap(pkB[5], pkB[7], false, false);
      i32x4 t3 = {(int)w6[0], (int)w7[0], (int)w6[1], (int)w7[1]};
      pf[3] = __builtin_bit_cast(bf16x8, t3);
    }

    // O^T += V^T P^T
#pragma unroll
    for (int ks = 0; ks < 4; ++ks)
      oA = __builtin_amdgcn_mfma_f32_32x32x16_bf16(vfA[ks], pf[ks], oA, 0, 0, 0);
#pragma unroll
    for (int ks = 0; ks < 4; ++ks)
      oB = __builtin_amdgcn_mfma_f32_32x32x16_bf16(vfB[ks], pf[ks], oB, 0, 0, 0);
  }

  // ---- write partials to LDS ----
  if (hi == 0) {
    Ml[wave][0][lq] = m;
    Ml[wave][1][lq] = l;
  }
#pragma unroll
  for (int r = 0; r < 16; ++r) {
    const int dhA = (r & 3) + 8 * (r >> 2) + 4 * hi;
    Ol[wave][dhA][lq] = oA[r];
    Ol[wave][dhA + 32][lq] = oB[r];
  }
  __syncthreads();

  // ---- combine: thread -> (col = tid>>3, dh0 = (tid&7)*8) ----
  const int col = tid >> 3;
  const int dh0 = (tid & 7) * 8;
  float mw[4];
  float M = -1e30f;
#pragma unroll
  for (int w = 0; w < 4; ++w) { mw[w] = Ml[w][0][col]; M = fmaxf(M, mw[w]); }
  float scw[4];
  float lsum = 0.f;
#pragma unroll
  for (int w = 0; w < 4; ++w) {
    scw[w] = __expf(mw[w] - M);
    lsum += scw[w] * Ml[w][1][col];
  }
  const float inv = 1.0f / lsum;
  const int b = bh >> 4, h = bh & 15;
  u16* dst = Ab + ((size_t)b * 2048 + q0 + col) * 1024 + h * 64 + dh0;
  ushort4 w0, w1;
  u16 tmp[8];
#pragma unroll
  for (int i = 0; i < 8; ++i) {
    const int dh = dh0 + i;
    float v = 0.f;
#pragma unroll
    for (int w = 0; w < 4; ++w) v += scw[w] * Ol[w][dh][col];
    tmp[i] = f2bf(v * inv);
  }
  w0.x = tmp[0]; w0.y = tmp[1]; w0.z = tmp[2]; w0.w = tmp[3];
  w1.x = tmp[4]; w1.y = tmp[5]; w1.z = tmp[6]; w1.w = tmp[7];
  *reinterpret_cast<ushort4*>(dst) = w0;
  *reinterpret_cast<ushort4*>(dst + 4) = w1;
}

extern "C" void kernel_launch(void* const* d_in, const int* in_sizes, int n_in,
                              void* d_out, int out_size, void* d_ws, size_t ws_size,
                              hipStream_t stream) {
  const float* x      = (const float*)d_in[0];
  const float* W_attn = (const float*)d_in[1];
  const float* b_attn = (const float*)d_in[2];
  const float* W_proj = (const float*)d_in[3];
  const float* b_proj = (const float*)d_in[4];
  float* out = (float*)d_out;

  u16* xb  = (u16*)d_ws;                      // [4096][1024] bf16
  u16* Wat = xb + (size_t)4096 * 1024;        // [3072][1024] bf16 (W_attn^T)
  u16* Wpt = Wat + (size_t)3072 * 1024;       // [1024][1024] bf16 (W_proj^T)
  u16* Qh  = Wpt + (size_t)1024 * 1024;       // [2,16,2048,64] bf16 (pre-scaled 1/8)
  u16* Kh  = Qh + (size_t)4194304;            // [2,16,2048,64] bf16
  u16* VhT = Kh + (size_t)4194304;            // [2,16,64,2048] bf16
  u16* Ab  = VhT + (size_t)4194304;           // [4096][1024] bf16

  cast_bf16_kernel<<<4096, 256, 0, stream>>>(x, xb, 4096 * 1024 / 4);
  transpose_cast<<<dim3(96, 32), dim3(32, 8), 0, stream>>>(W_attn, Wat, 1024, 3072);
  transpose_cast<<<dim3(32, 32), dim3(32, 8), 0, stream>>>(W_proj, Wpt, 1024, 1024);
  gemm_qkv<<<dim3(24, 32), 256, 0, stream>>>(xb, Wat, b_attn, Qh, Kh, VhT, 1024);
  attn_fwd<<<dim3(2048), 256, 0, stream>>>(Qh, Kh, VhT, Ab);
  gemm_proj<<<dim3(16, 32), 256, 0, stream>>>(Ab, Wpt, b_proj, out, 1024, 1024);
}